// Round 3
// baseline (1795.070 us; speedup 1.0000x reference)
//
#include <hip/hip_runtime.h>
#include <hip/hip_bf16.h>

// Problem constants (from reference)
#define BB 4
#define NN 262144          // 2^18
#define FF 64
#define SS 1024
#define OUTF 64

// Workspace layout (float offsets)
#define SUMS_R 0                     // [B][S][F] = 262144
#define SUMS_C 262144                // [B][S][F]
#define CNT_R  524288                // [B][S] = 4096
#define CNT_C  528384
#define GSUM   532480                // [B][F] = 256
#define ZERO_FLOATS 532736           // everything above must be zeroed
#define M_OFF  532736                // 4 x [64][64] = 16384
#define BIAS_OFF 549120              // [64]
#define P2_OFF 549184                // [B][S][F]
#define P3_OFF 811328                // [B][S][F]
#define GPROJ_OFF 1073472            // [B][F]
// total = 1073728 floats = ~4.3 MB

// ---------------- K0: fold weight matrices -----------------------------------
// M[i] = W_i @ W_out[i*64:(i+1)*64, :]   (i: 0=self,1=row,2=col,3=glob)
// bias_total[c] = b_out[c] + sum_i b_i @ W_out_i[:, c]
__global__ __launch_bounds__(256) void k_prep(
    const float* __restrict__ W_self, const float* __restrict__ b_self,
    const float* __restrict__ W_row,  const float* __restrict__ b_row,
    const float* __restrict__ W_col,  const float* __restrict__ b_col,
    const float* __restrict__ W_glob, const float* __restrict__ b_glob,
    const float* __restrict__ W_out,  const float* __restrict__ b_out,
    float* __restrict__ M, float* __restrict__ bias)
{
    int blk = blockIdx.x, t = threadIdx.x;
    if (blk < 64) {
        int i = blk >> 4;
        const float* W = (i == 0) ? W_self : (i == 1) ? W_row : (i == 2) ? W_col : W_glob;
        int e = ((blk & 15) << 8) + t;     // 0..4095 within matrix i
        int r = e >> 6, c = e & 63;
        float acc = 0.f;
        #pragma unroll
        for (int k = 0; k < 64; ++k)
            acc = fmaf(W[r * 64 + k], W_out[(i * 64 + k) * 64 + c], acc);
        M[i * 4096 + e] = acc;
    } else {
        if (t < 64) {
            float acc = b_out[t];
            const float* bs_[4] = { b_self, b_row, b_col, b_glob };
            for (int i = 0; i < 4; ++i)
                for (int k = 0; k < 64; ++k)
                    acc = fmaf(bs_[i][k], W_out[(i * 64 + k) * 64 + t], acc);
            bias[t] = acc;
        }
    }
}

// ---------------- K_idx: index passthrough as float --------------------------
// The tuple output buffer is read back as float32; output 0 must hold
// float(index) values, not raw int bits.
__global__ __launch_bounds__(256) void k_idx(
    const int* __restrict__ idx, float* __restrict__ outi)
{
    long long e = ((long long)blockIdx.x * 256 + threadIdx.x) * 4;
    int4 v = *(const int4*)(idx + e);
    float4 f = make_float4((float)v.x, (float)v.y, (float)v.z, (float)v.w);
    *(float4*)(outi + e) = f;
}

// ---------------- K1: segment-sum scatter (row & col) ------------------------
// Grid: 256 blocks = B(4) x FG(4 feature groups of 16) x CH(16 row chunks of 16384)
// LDS: row sums [16][1024], col sums [16][1024] (feature-major, XOR-swizzled),
//      cnt_row[1024], cnt_col[1024]  -> 136 KiB dynamic
__global__ __launch_bounds__(256) void k_scatter(
    const float* __restrict__ value, const int* __restrict__ idx,
    float* __restrict__ sums_r, float* __restrict__ sums_c,
    float* __restrict__ cnt_r, float* __restrict__ cnt_c,
    float* __restrict__ gsum)
{
    extern __shared__ float lds[];
    const int t  = threadIdx.x;
    const int blk = blockIdx.x;
    const int b  = blk >> 6;
    const int fg = (blk >> 4) & 3;
    const int ch = blk & 15;

    for (int w = t; w < 34816; w += 256) lds[w] = 0.f;
    __syncthreads();

    const int fsub = t & 3;        // which float4 of the 16-feature group
    const int rl   = t >> 2;       // row-in-iteration 0..63
    const long long rowbase = ((long long)b << 18) + ((long long)ch << 14);
    const float* vbase = value + (rowbase << 6) + (fg * 16 + fsub * 4);
    const int2*  ibase = (const int2*)idx + rowbase;

    for (int i = 0; i < 256; i += 4) {
        float4 v[4]; int2 sg[4];
        #pragma unroll
        for (int u = 0; u < 4; ++u) {
            int r = rl + (i + u) * 64;
            v[u]  = *(const float4*)(vbase + ((long long)r << 6));
            sg[u] = ibase[r];
        }
        #pragma unroll
        for (int u = 0; u < 4; ++u) {
            int sr = sg[u].x, sc = sg[u].y;
            #pragma unroll
            for (int j = 0; j < 4; ++j) {
                int f = fsub * 4 + j;
                int swz = (2 * f) & 31;
                float vj = (&v[u].x)[j];
                atomicAdd(&lds[f * 1024 + (sr ^ swz)], vj);
                atomicAdd(&lds[16384 + f * 1024 + (sc ^ swz)], vj);
            }
            if (fg == 0 && fsub == 0) {
                atomicAdd(&lds[32768 + sr], 1.f);
                atomicAdd(&lds[33792 + sc], 1.f);
            }
        }
    }
    __syncthreads();

    // flush per-block partial sums to global
    float* gr = sums_r + ((long long)b << 16) + fg * 16;
    float* gc = sums_c + ((long long)b << 16) + fg * 16;
    for (int e = t; e < 16384; e += 256) {
        int f = e >> 10, s = e & 1023;
        int w = f * 1024 + (s ^ ((2 * f) & 31));
        atomicAdd(gr + s * 64 + f, lds[w]);
        atomicAdd(gc + s * 64 + f, lds[16384 + w]);
    }
    if (fg == 0) {
        for (int e = t; e < 1024; e += 256) {
            atomicAdd(cnt_r + b * 1024 + e, lds[32768 + e]);
            atomicAdd(cnt_c + b * 1024 + e, lds[33792 + e]);
        }
    }
    // global-mean partial: sum of row-plane over segs
    {
        int f = t & 15, sg0 = t >> 4;
        int swz = (2 * f) & 31;
        float p = 0.f;
        for (int s = sg0 * 64; s < sg0 * 64 + 64; ++s)
            p += lds[f * 1024 + (s ^ swz)];
        atomicAdd(gsum + b * 64 + fg * 16 + f, p);
    }
}

// ---------------- K2: build gather tables ------------------------------------
// P2[b,s,:] = (sums_r/(cnt+1e-9)) @ M2 ; P3 likewise with M3
// Gproj[b,:] = (gsum/N) @ M4 + bias_total
__global__ __launch_bounds__(256) void k_tables(
    const float* __restrict__ sums_r, const float* __restrict__ sums_c,
    const float* __restrict__ cnt_r,  const float* __restrict__ cnt_c,
    const float* __restrict__ gsum,   const float* __restrict__ bias,
    const float* __restrict__ M2, const float* __restrict__ M3,
    const float* __restrict__ M4,
    float* __restrict__ P2, float* __restrict__ P3, float* __restrict__ Gp)
{
    int blk = blockIdx.x, t = threadIdx.x;
    if (blk < 2048) {
        int which = blk >> 10;             // 0 -> P2(row), 1 -> P3(col)
        int e = ((blk & 1023) << 8) + t;   // 0..262143
        int f = e & 63;
        int bs = e >> 6;                   // b*1024 + s
        const float* sums = which ? sums_c : sums_r;
        const float* cnt  = which ? cnt_c  : cnt_r;
        const float* Mx   = which ? M3 : M2;
        float inv = 1.f / (cnt[bs] + 1e-9f);
        const float* srow = sums + ((long long)bs << 6);
        float acc = 0.f;
        #pragma unroll
        for (int k = 0; k < 64; ++k)
            acc = fmaf(srow[k], Mx[k * 64 + f], acc);
        float* P = which ? P3 : P2;
        P[((long long)bs << 6) + f] = acc * inv;
    } else if (blk == 2048) {
        int f = t & 63, b = t >> 6;
        float acc = 0.f;
        #pragma unroll
        for (int k = 0; k < 64; ++k)
            acc = fmaf(gsum[b * 64 + k], M4[k * 64 + f], acc);
        Gp[b * 64 + f] = acc * (1.f / 262144.f) + bias[f];
    }
}

// ---------------- K3: main fused pass ----------------------------------------
// lane = output feature. M1 column in registers. Row data via wave-uniform
// (scalar) loads; P2/P3 gathers are coalesced 256B reads.
__global__ __launch_bounds__(256) void k_main(
    const float* __restrict__ value, const int* __restrict__ idx,
    const float* __restrict__ M1, const float* __restrict__ P2,
    const float* __restrict__ P3, const float* __restrict__ Gp,
    float* __restrict__ out)
{
    const int lane = threadIdx.x & 63;
    float m1[64];
    #pragma unroll
    for (int k = 0; k < 64; ++k) m1[k] = M1[k * 64 + lane];

    const int wave = blockIdx.x * 4 + (threadIdx.x >> 6);
    const int RPW = (BB * NN) / (2048 * 4);   // 128 rows per wave, exact
    long long r0 = (long long)wave * RPW;

    for (int rr = 0; rr < RPW; ++rr) {
        unsigned ru = __builtin_amdgcn_readfirstlane((unsigned)(r0 + rr));
        const float* vrow = value + ((long long)ru << 6);
        const int*   ip   = idx + ((long long)ru << 1);
        int b  = ru >> 18;
        int ir = ip[0], ic = ip[1];
        const float* p2 = P2 + ((long long)((b << 10) + ir) << 6);
        const float* p3 = P3 + ((long long)((b << 10) + ic) << 6);
        float extra = p2[lane] + p3[lane] + Gp[(b << 6) + lane];
        float a0 = 0.f, a1 = 0.f, a2 = 0.f, a3 = 0.f;
        #pragma unroll
        for (int k = 0; k < 64; k += 4) {
            float4 v = *(const float4*)(vrow + k);
            a0 = fmaf(v.x, m1[k + 0], a0);
            a1 = fmaf(v.y, m1[k + 1], a1);
            a2 = fmaf(v.z, m1[k + 2], a2);
            a3 = fmaf(v.w, m1[k + 3], a3);
        }
        float acc = (a0 + a1) + (a2 + a3) + extra;
        out[(((long long)ru) << 6) + lane] = fmaxf(acc, 0.01f * acc);
    }
}

// ---------------- launcher ---------------------------------------------------
extern "C" void kernel_launch(void* const* d_in, const int* in_sizes, int n_in,
                              void* d_out, int out_size, void* d_ws, size_t ws_size,
                              hipStream_t stream) {
    const int*   idx    = (const int*)d_in[0];
    const float* value  = (const float*)d_in[1];
    const float* W_self = (const float*)d_in[2];
    const float* b_self = (const float*)d_in[3];
    const float* W_row  = (const float*)d_in[4];
    const float* b_row  = (const float*)d_in[5];
    const float* W_col  = (const float*)d_in[6];
    const float* b_col  = (const float*)d_in[7];
    const float* W_glob = (const float*)d_in[8];
    const float* b_glob = (const float*)d_in[9];
    const float* W_out  = (const float*)d_in[10];
    const float* b_out  = (const float*)d_in[11];

    float* ws = (float*)d_ws;

    // zero the accumulator region (ws is poisoned 0xAA before every launch)
    hipMemsetAsync(ws, 0, (size_t)ZERO_FLOATS * sizeof(float), stream);

    // tuple output: (index, out) -> output 0 is read back as float32, so
    // convert index ints to their float values.
    float* outi = (float*)d_out;
    k_idx<<<(BB * NN * 2) / (256 * 4), 256, 0, stream>>>(idx, outi);
    float* outf = (float*)d_out + (size_t)BB * NN * 2;

    k_prep<<<65, 256, 0, stream>>>(W_self, b_self, W_row, b_row, W_col, b_col,
                                   W_glob, b_glob, W_out, b_out,
                                   ws + M_OFF, ws + BIAS_OFF);

    hipFuncSetAttribute((const void*)k_scatter,
                        hipFuncAttributeMaxDynamicSharedMemorySize, 139264);
    k_scatter<<<256, 256, 139264, stream>>>(value, idx,
                                            ws + SUMS_R, ws + SUMS_C,
                                            ws + CNT_R, ws + CNT_C, ws + GSUM);

    k_tables<<<2049, 256, 0, stream>>>(ws + SUMS_R, ws + SUMS_C,
                                       ws + CNT_R, ws + CNT_C,
                                       ws + GSUM, ws + BIAS_OFF,
                                       ws + M_OFF + 4096,      // M2
                                       ws + M_OFF + 2 * 4096,  // M3
                                       ws + M_OFF + 3 * 4096,  // M4
                                       ws + P2_OFF, ws + P3_OFF, ws + GPROJ_OFF);

    k_main<<<2048, 256, 0, stream>>>(value, idx, ws + M_OFF,
                                     ws + P2_OFF, ws + P3_OFF, ws + GPROJ_OFF,
                                     outf);
}